// Round 6
// baseline (335.757 us; speedup 1.0000x reference)
//
#include <hip/hip_runtime.h>
#include <hip/hip_bf16.h>
#include <cstdint>
#include <cstddef>

// ---------------- problem constants ----------------
#define B_    32
#define S_    8192
#define D_    128
#define V_    21
#define VP_   22                 // vocab + zero-pad token (id 21 -> zero embedding row)
#define T_    (VP_*VP_*VP_)      // 10648 triples
#define TPAD_ 10656              // padded to multiple of 16 for MFMA tiles
#define C1_   256
#define C2_   128
#define NPOS_ (B_*S_)            // 262144
#define CH_   128                // conv3 positions per block
#define NCHUNK_ 64               // S_/CH_

using bf16x8 = __attribute__((ext_vector_type(8))) short;
using f32x4  = __attribute__((ext_vector_type(4))) float;
using u32x4  = __attribute__((ext_vector_type(4))) unsigned;

__device__ inline unsigned short f2bf(float f) {
  union { float f; unsigned u; } v; v.f = f;
  unsigned r = v.u + 0x7fffu + ((v.u >> 16) & 1u);
  return (unsigned short)(r >> 16);
}
__device__ inline float bf2f(unsigned short h) {
  union { unsigned u; float f; } v; v.u = ((unsigned)h) << 16; return v.f;
}

// ---------------- K1: G build + weight transposes (merged) ----------------
__global__ void k_prep(const float* __restrict__ W1, const float* __restrict__ emb,
                       const float* __restrict__ W2, const float* __restrict__ W3,
                       float* __restrict__ G, unsigned short* __restrict__ Wr2,
                       unsigned short* __restrict__ W3r) {
  int bid = blockIdx.x;
  if (bid < 66) {
    int v = bid % VP_, k = bid / VP_, o = threadIdx.x;   // block 256
    __shared__ float e[D_];
    if (o < D_) e[o] = (v < V_) ? emb[v * D_ + o] : 0.f;
    __syncthreads();
    float acc = 0.f;
    if (v < V_) {
      for (int i = 0; i < D_; ++i) acc += W1[o * (D_ * 3) + i * 3 + k] * e[i];
    }
    G[(k * VP_ + v) * C1_ + o] = acc;
  } else {
    int idx = (bid - 66) * 256 + threadIdx.x;
    if (idx < 384 * 256) {
      int r = idx >> 8, o = idx & 255;
      int k = r >> 7, p = r & 127;
      Wr2[idx] = f2bf(W2[(p * C1_ + o) * 3 + k]);
    } else {
      int j = idx - 384 * 256;
      if (j < 128 * 384) {
        int q = j / 384, kk = j % 384;
        int k = kk >> 7, p = kk & 127;
        W3r[q * 384 + kk] = f2bf(W3[(q * C2_ + p) * 3 + k]);
      }
    }
  }
}

// ---------------- K3: triple index + histogram + social partials (fused) ----------
__global__ void k_tidx_social(const int* __restrict__ ids, int* __restrict__ tIdx,
                              int* __restrict__ cnt, int* __restrict__ socC,
                              int* __restrict__ socS, int* __restrict__ socF,
                              int* __restrict__ socL) {
  int idx = blockIdx.x * 256 + threadIdx.x;
  int b = idx >> 13, s = idx & (S_ - 1);
  const int* row = ids + b * S_;
  int a = (s > 0)      ? row[s - 1] : V_;
  int m = row[s];
  int c = (s < S_ - 1) ? row[s + 1] : V_;
  int t = (a * VP_ + m) * VP_ + c;
  tIdx[idx] = t;
  atomicAdd(&cnt[t], 1);

  bool sm = (m == 1) | (m == 18);
  bool pm = (a == 1) | (a == 18);          // s==0 -> a==V_ -> false (matches ref)
  unsigned long long bm = __ballot(sm);
  unsigned long long bs = __ballot(sm && !pm);
  __shared__ int l0, l1, l2, l3;
  if (threadIdx.x == 0) { l0 = 0; l1 = 0; l2 = 0; l3 = 0; }
  __syncthreads();
  int lane = threadIdx.x & 63;
  // first/last: encode first as max(S-1-s) so zero-init works
  int fc = sm ? (S_ - 1 - s) : 0;
  int lv = sm ? s : 0;
#pragma unroll
  for (int off = 1; off < 64; off <<= 1) {
    fc = max(fc, __shfl_xor(fc, off));
    lv = max(lv, __shfl_xor(lv, off));
  }
  if (lane == 0) {
    atomicAdd(&l0, (int)__popcll(bm));
    atomicAdd(&l1, (int)__popcll(bs));
    atomicMax(&l2, fc);
    atomicMax(&l3, lv);
  }
  __syncthreads();
  if (threadIdx.x == 0) {
    atomicAdd(&socC[b], l0); atomicAdd(&socS[b], l1);
    atomicMax(&socF[b], l2); atomicMax(&socL[b], l3);
  }
}

// ---------------- K4: BN1 stats only (weighted by histogram) ----------
__global__ void k_stats1(const float* __restrict__ G, const float* __restrict__ b1,
                         const int* __restrict__ cnt,
                         float* __restrict__ m1acc, float* __restrict__ v1acc) {
  int o = threadIdx.x;   // 256
  float bb = b1[o];
  float s = 0.f, sq = 0.f;
  int t0 = blockIdx.x * 16;
#pragma unroll 4
  for (int i = 0; i < 16; ++i) {
    int t = t0 + i;
    if (t >= T_) break;
    int a = t / (VP_ * VP_), m = (t / VP_) % VP_, c = t % VP_;
    float x = G[a * C1_ + o] + G[(VP_ + m) * C1_ + o] + G[(2 * VP_ + c) * C1_ + o] + bb;
    float w = (float)cnt[t];
    s += w * x; sq += w * x * x;
  }
  atomicAdd(&m1acc[o], s);
  atomicAdd(&v1acc[o], sq);
}

// ---------------- K7: Z1[t] = bf16(relu(bn1(G-sum))), recomputed from G ----------
__global__ void k_z1(const float* __restrict__ G, const float* __restrict__ b1,
                     const float* __restrict__ m1a, const float* __restrict__ v1a,
                     const float* __restrict__ g1, const float* __restrict__ be1,
                     unsigned* __restrict__ Z1u) {
  int tid = threadIdx.x;
  int t = blockIdx.x * 2 + (tid >> 7);
  int o = (tid & 127) * 2;
  float m0 = m1a[o] * (1.f / NPOS_), m1v = m1a[o + 1] * (1.f / NPOS_);
  float a0 = g1[o]     * rsqrtf(v1a[o]     * (1.f / NPOS_) - m0 * m0   + 1e-5f);
  float a1 = g1[o + 1] * rsqrtf(v1a[o + 1] * (1.f / NPOS_) - m1v * m1v + 1e-5f);
  float c0 = be1[o] - m0 * a0, c1 = be1[o + 1] - m1v * a1;
  unsigned pk = 0;
  if (t < T_) {
    int a = t / (VP_ * VP_), m = (t / VP_) % VP_, c = t % VP_;
    float2 xa = *(const float2*)(G + (size_t)a * C1_ + o);
    float2 xm = *(const float2*)(G + (size_t)(VP_ + m) * C1_ + o);
    float2 xc = *(const float2*)(G + (size_t)(2 * VP_ + c) * C1_ + o);
    float x0 = xa.x + xm.x + xc.x + b1[o];
    float x1 = xa.y + xm.y + xc.y + b1[o + 1];
    float z0 = fmaxf(a0 * x0 + c0, 0.f);
    float z1 = fmaxf(a1 * x1 + c1, 0.f);
    pk = (unsigned)f2bf(z0) | ((unsigned)f2bf(z1) << 16);
  }
  Z1u[(size_t)t * 128 + (tid & 127)] = pk;
}

// ---------------- K9: H GEMM  H[t][r] = sum_o Z1[t][o]*Wr2[r][o]  (bf16 MFMA) ----
// grid (167, 3): block.y owns 8 nt (4 pairs, 2 interleaved acc chains).
__global__ void __launch_bounds__(256) k_hgemm(const unsigned short* __restrict__ Z1,
                                               const unsigned short* __restrict__ Wr2,
                                               unsigned short* __restrict__ H) {
  int wave = threadIdx.x >> 6, lane = threadIdx.x & 63;
  int mt = blockIdx.x * 4 + wave;                 // m-tile (16 t-rows)
  if (mt >= TPAD_ / 16) return;
  int nt0 = blockIdx.y * 8;
  int rc   = lane & 15;                            // A-row / B-col / D-col
  int kgrp = lane >> 4;                            // k-offset group
  bf16x8 af[8];
  const unsigned short* Arow = Z1 + (size_t)(mt * 16 + rc) * C1_ + kgrp * 8;
#pragma unroll
  for (int st = 0; st < 8; ++st) af[st] = *(const bf16x8*)(Arow + st * 32);
#pragma unroll
  for (int ntp = 0; ntp < 4; ++ntp) {
    int ntA = nt0 + ntp * 2, ntB = ntA + 1;
    f32x4 accA = {0.f, 0.f, 0.f, 0.f}, accB = {0.f, 0.f, 0.f, 0.f};
    const unsigned short* BrA = Wr2 + (size_t)(ntA * 16 + rc) * C1_ + kgrp * 8;
    const unsigned short* BrB = Wr2 + (size_t)(ntB * 16 + rc) * C1_ + kgrp * 8;
#pragma unroll
    for (int st = 0; st < 8; ++st) {
      bf16x8 bA = *(const bf16x8*)(BrA + st * 32);
      bf16x8 bB = *(const bf16x8*)(BrB + st * 32);
      accA = __builtin_amdgcn_mfma_f32_16x16x32_bf16(af[st], bA, accA, 0, 0, 0);
      accB = __builtin_amdgcn_mfma_f32_16x16x32_bf16(af[st], bB, accB, 0, 0, 0);
    }
#pragma unroll
    for (int r = 0; r < 4; ++r) {
      int m = mt * 16 + kgrp * 4 + r;              // D row
      H[(size_t)m * 384 + ntA * 16 + rc] = f2bf(accA[r]);
      H[(size_t)m * 384 + ntB * 16 + rc] = f2bf(accB[r]);
    }
  }
}

// ---------------- K10: y2 gather (ONCE) + BN2 stats + y2 store ----------------
#define YPB 256
__global__ void __launch_bounds__(256, 3) k_y2stats(const int* __restrict__ tIdx,
        const unsigned short* __restrict__ H, const float* __restrict__ b2,
        unsigned short* __restrict__ y2, float* __restrict__ sum, float* __restrict__ sq) {
  int lane16 = threadIdx.x & 15;       // channel slice: ch = lane16*8 .. +8
  int pgrp   = threadIdx.x >> 4;       // 0..15
  int base0  = blockIdx.x * YPB;
  float bb[8];
  const float* b2s = b2 + lane16 * 8;
#pragma unroll
  for (int j = 0; j < 8; ++j) bb[j] = b2s[j];
  float sAcc[8] = {0,0,0,0,0,0,0,0}, qAcc[8] = {0,0,0,0,0,0,0,0};

  for (int ib = 0; ib < 2; ++ib) {
    int base = base0 + ib * 128;
    int tA[8], tM[8], tC[8];
#pragma unroll
    for (int i = 0; i < 8; ++i) {
      int pos = base + i * 16 + pgrp;
      int s = pos & (S_ - 1);
      const int* tr = tIdx + (pos & ~(S_ - 1));
      tM[i] = tr[s];
      int sa = s > 0 ? s - 1 : 0;
      int sc = s < S_ - 1 ? s + 1 : s;
      int ta = tr[sa], tc = tr[sc];
      tA[i] = (s > 0)      ? ta : T_;
      tC[i] = (s < S_ - 1) ? tc : T_;
    }
    bf16x8 h0[8], h1[8], h2[8];
#pragma unroll
    for (int i = 0; i < 8; ++i)
      h1[i] = *(const bf16x8*)(H + (size_t)tM[i] * 384 + 128 + lane16 * 8);
#pragma unroll
    for (int i = 0; i < 8; ++i)
      h0[i] = *(const bf16x8*)(H + (size_t)tA[i] * 384 +   0 + lane16 * 8);
#pragma unroll
    for (int i = 0; i < 8; ++i)
      h2[i] = *(const bf16x8*)(H + (size_t)tC[i] * 384 + 256 + lane16 * 8);

#pragma unroll
    for (int i = 0; i < 8; ++i) {
      int pos = base + i * 16 + pgrp;
      float y[8];
#pragma unroll
      for (int j = 0; j < 8; ++j) {
        y[j] = bb[j] + bf2f((unsigned short)h0[i][j]) + bf2f((unsigned short)h1[i][j])
                     + bf2f((unsigned short)h2[i][j]);
        sAcc[j] += y[j]; qAcc[j] += y[j] * y[j];
      }
      u32x4 pk;
      pk[0] = (unsigned)f2bf(y[0]) | ((unsigned)f2bf(y[1]) << 16);
      pk[1] = (unsigned)f2bf(y[2]) | ((unsigned)f2bf(y[3]) << 16);
      pk[2] = (unsigned)f2bf(y[4]) | ((unsigned)f2bf(y[5]) << 16);
      pk[3] = (unsigned)f2bf(y[6]) | ((unsigned)f2bf(y[7]) << 16);
      *(u32x4*)(y2 + (size_t)pos * C2_ + lane16 * 8) = pk;
    }
  }

  __shared__ float ls[128], lq[128];
  if (threadIdx.x < 128) { ls[threadIdx.x] = 0.f; lq[threadIdx.x] = 0.f; }
  __syncthreads();
  int lane = threadIdx.x & 63;
#pragma unroll
  for (int j = 0; j < 8; ++j) {
    float v = sAcc[j], q = qAcc[j];
    v += __shfl_xor(v, 16); v += __shfl_xor(v, 32);
    q += __shfl_xor(q, 16); q += __shfl_xor(q, 32);
    if (lane < 16) { atomicAdd(&ls[lane16 * 8 + j], v); atomicAdd(&lq[lane16 * 8 + j], q); }
  }
  __syncthreads();
  if (threadIdx.x < 128) {
    atomicAdd(&sum[threadIdx.x], ls[threadIdx.x]);
    atomicAdd(&sq[threadIdx.x],  lq[threadIdx.x]);
  }
}

// ---------------- K12: conv3, restructured dataflow ----------------
// 256 thr (4 waves), CH=128 pos per block. LDS z2 tile [130] rows x 256 B, 4-bit XOR swizzle.
// Each wave owns 2 pos-tiles x ALL 8 q-subtiles: every B ds_read feeds 8 MFMAs.
// A (W3r, 96 KB, L2-resident) streamed from global per st. Cross-wave LDS reduce epilogue.
__global__ void __launch_bounds__(256, 4) k_conv3(const unsigned short* __restrict__ y2,
      const float* __restrict__ s2a, const float* __restrict__ q2a,
      const float* __restrict__ g2, const float* __restrict__ be2,
      const unsigned short* __restrict__ W3r, const float* __restrict__ b3,
      float* __restrict__ part) {
  __shared__ unsigned short z2s[130 * 128];       // 33280 B
  int b     = blockIdx.x >> 6;                    // NCHUNK_=64 chunks per batch row
  int chunk = blockIdx.x & 63;
  int s0    = chunk * CH_;
  int tid = threadIdx.x;

  // ---- phase 1: stream y2 rows s0-1 .. s0+128, bn2(inline)+relu, swizzled LDS store ----
  {
    int lane16 = tid & 15;           // 8-channel slice
    int rowg   = tid >> 4;           // 0..15
    const unsigned short* ybase = y2 + (size_t)b * S_ * C2_ + lane16 * 8;
    bf16x8 hv[9];
    int uu[9];
#pragma unroll
    for (int it = 0; it < 9; ++it) {
      int pos = it * 16 + rowg;
      int u = s0 - 1 + pos;
      uu[it] = u;
      int uc = min(max(u, 0), S_ - 1);
      hv[it] = *(const bf16x8*)(ybase + (size_t)uc * C2_);
    }
    float aa[8], cc[8];
#pragma unroll
    for (int j = 0; j < 8; ++j) {
      int ch = lane16 * 8 + j;
      float mm = s2a[ch] * (1.f / NPOS_);
      float vv = q2a[ch] * (1.f / NPOS_) - mm * mm;
      float a  = g2[ch] * rsqrtf(vv + 1e-5f);
      aa[j] = a; cc[j] = be2[ch] - mm * a;
    }
#pragma unroll
    for (int it = 0; it < 9; ++it) {
      int pos = it * 16 + rowg;
      bool valid = (uu[it] >= 0) & (uu[it] < S_);
      float z[8];
#pragma unroll
      for (int j = 0; j < 8; ++j)
        z[j] = fmaxf(aa[j] * bf2f((unsigned short)hv[it][j]) + cc[j], 0.f);
      u32x4 pk;
      pk[0] = (unsigned)f2bf(z[0]) | ((unsigned)f2bf(z[1]) << 16);
      pk[1] = (unsigned)f2bf(z[2]) | ((unsigned)f2bf(z[3]) << 16);
      pk[2] = (unsigned)f2bf(z[4]) | ((unsigned)f2bf(z[5]) << 16);
      pk[3] = (unsigned)f2bf(z[6]) | ((unsigned)f2bf(z[7]) << 16);
      if (!valid) pk = (u32x4){0, 0, 0, 0};
      if (pos < CH_ + 2) {
        int byte = (lane16 * 16) ^ ((pos & 15) << 4);   // 4-bit XOR swizzle
        *(u32x4*)((char*)z2s + pos * 256 + byte) = pk;
      }
    }
  }
  __syncthreads();

  // ---- phase 2: MFMA. Wave owns pos-tiles {wave*2, wave*2+1} x q-subtiles 0..7 ----
  int wave = tid >> 6, lane = tid & 63;
  int rc = lane & 15, kgrp = lane >> 4;
  f32x4 acc[8][2];
#pragma unroll
  for (int qt = 0; qt < 8; ++qt) {
    acc[qt][0] = (f32x4){0.f, 0.f, 0.f, 0.f};
    acc[qt][1] = (f32x4){0.f, 0.f, 0.f, 0.f};
  }
  const unsigned short* Wbase = W3r + (size_t)rc * 384 + kgrp * 8;
#pragma unroll
  for (int st = 0; st < 12; ++st) {
    int k = st >> 2, pb = st & 3;
    int pbyte = pb * 64 + kgrp * 16;
    int pos0 = (wave * 2) * 16 + rc + k;
    int pos1 = pos0 + 16;
    bf16x8 bfr0 = *(const bf16x8*)((const char*)z2s + pos0 * 256 + (pbyte ^ ((pos0 & 15) << 4)));
    bf16x8 bfr1 = *(const bf16x8*)((const char*)z2s + pos1 * 256 + (pbyte ^ ((pos1 & 15) << 4)));
#pragma unroll
    for (int qt = 0; qt < 8; ++qt) {
      bf16x8 af = *(const bf16x8*)(Wbase + (size_t)qt * 16 * 384 + st * 32);
      acc[qt][0] = __builtin_amdgcn_mfma_f32_16x16x32_bf16(af, bfr0, acc[qt][0], 0, 0, 0);
      acc[qt][1] = __builtin_amdgcn_mfma_f32_16x16x32_bf16(af, bfr1, acc[qt][1], 0, 0, 0);
    }
  }

  // ---- epilogue: +b3, ReLU, sum over 32 pos (2 tiles + shfl over rc), LDS cross-wave ----
  __syncthreads();                                // all z2s reads done; reuse as reduce buf
  float* red = (float*)z2s;                       // [4][128]
#pragma unroll
  for (int qt = 0; qt < 8; ++qt) {
    const float4 b3q = *(const float4*)(b3 + qt * 16 + kgrp * 4);
    float p0 = fmaxf(acc[qt][0][0] + b3q.x, 0.f) + fmaxf(acc[qt][1][0] + b3q.x, 0.f);
    float p1 = fmaxf(acc[qt][0][1] + b3q.y, 0.f) + fmaxf(acc[qt][1][1] + b3q.y, 0.f);
    float p2 = fmaxf(acc[qt][0][2] + b3q.z, 0.f) + fmaxf(acc[qt][1][2] + b3q.z, 0.f);
    float p3 = fmaxf(acc[qt][0][3] + b3q.w, 0.f) + fmaxf(acc[qt][1][3] + b3q.w, 0.f);
#pragma unroll
    for (int off = 1; off < 16; off <<= 1) {
      p0 += __shfl_xor(p0, off); p1 += __shfl_xor(p1, off);
      p2 += __shfl_xor(p2, off); p3 += __shfl_xor(p3, off);
    }
    if (rc == 0) {
      float* r4 = red + wave * 128 + qt * 16 + kgrp * 4;
      r4[0] = p0; r4[1] = p1; r4[2] = p2; r4[3] = p3;
    }
  }
  __syncthreads();
  if (tid < 128) {
    float v = red[tid] + red[128 + tid] + red[256 + tid] + red[384 + tid];
    part[((size_t)b * NCHUNK_ + chunk) * C2_ + tid] = v;
  }
}

// ---------------- K14: partial reduce + social finalize + output GEMV ----------------
__global__ void k_final(const float* __restrict__ part,
      const int* __restrict__ socC, const int* __restrict__ socS,
      const int* __restrict__ socF, const int* __restrict__ socL,
      const float* __restrict__ baseline,
      const float* __restrict__ Ws, const float* __restrict__ bs,
      const float* __restrict__ Wo, const float* __restrict__ bo,
      float* __restrict__ out) {
  int b = blockIdx.x, q = threadIdx.x;             // 128 threads
  __shared__ float h[256];
  __shared__ float st3[3];
  {
    float acc = 0.f;
    const float* pb = part + (size_t)b * NCHUNK_ * C2_ + q;
#pragma unroll 8
    for (int i = 0; i < NCHUNK_; ++i) acc += pb[i * C2_];
    h[q] = acc * (1.f / S_);
  }
  if (q == 0) {
    float total = (float)socC[b], nseg = (float)socS[b];
    int first = (S_ - 1) - socF[b], last = socL[b];
    float mu   = (nseg > 0.f) ? total / fmaxf(nseg, 1.f) : 0.f;
    float gap  = (nseg > 0.f) ? (float)(last - first + 1) - total : 0.f;
    float resp = (nseg > 1.f) ? gap / fmaxf(nseg - 1.f, 1.f) : 0.f;
    st3[0] = mu; st3[1] = nseg; st3[2] = resp;
    float den = baseline[b * 3 + 0] * baseline[b * 3 + 1] + 1e-10f;
    float sws = 1.f - mu * nseg / den;
    out[B_ * C2_ + b] = fminf(fmaxf(sws, 0.f), 1.f);
  }
  __syncthreads();
  h[128 + q] = Ws[q * 3] * st3[0] + Ws[q * 3 + 1] * st3[1] + Ws[q * 3 + 2] * st3[2] + bs[q];
  __syncthreads();
  float acc = bo[q];
  const float4* Wo4 = (const float4*)(Wo + q * 256);
#pragma unroll 8
  for (int j4 = 0; j4 < 64; ++j4) {
    float4 wv = Wo4[j4];
    acc += wv.x * h[j4 * 4] + wv.y * h[j4 * 4 + 1] + wv.z * h[j4 * 4 + 2] + wv.w * h[j4 * 4 + 3];
  }
  out[b * C2_ + q] = acc;
}

// ---------------- launch ----------------
extern "C" void kernel_launch(void* const* d_in, const int* in_sizes, int n_in,
                              void* d_out, int out_size, void* d_ws, size_t ws_size,
                              hipStream_t stream) {
  const int*   ids = (const int*)  d_in[0];
  const float* bas = (const float*)d_in[1];
  const float* emb = (const float*)d_in[2];
  const float* W1  = (const float*)d_in[3];
  const float* b1  = (const float*)d_in[4];
  const float* g1  = (const float*)d_in[5];
  const float* be1 = (const float*)d_in[6];
  const float* W2  = (const float*)d_in[7];
  const float* b2  = (const float*)d_in[8];
  const float* g2  = (const float*)d_in[9];
  const float* be2 = (const float*)d_in[10];
  const float* W3  = (const float*)d_in[11];
  const float* b3  = (const float*)d_in[12];
  const float* Ws  = (const float*)d_in[13];
  const float* bs  = (const float*)d_in[14];
  const float* Wo  = (const float*)d_in[15];
  const float* bo  = (const float*)d_in[16];
  float* out = (float*)d_out;

  char* w = (char*)d_ws;
  size_t off = 0;
  auto alloc = [&](size_t bytes) -> size_t {
    size_t o = off; off = (off + bytes + 255) & ~(size_t)255; return o;
  };
  size_t o_cnt  = alloc(T_ * 4);
  size_t o_m1   = alloc(C1_ * 4);
  size_t o_v1   = alloc(C1_ * 4);
  size_t o_s2   = alloc(C2_ * 4);
  size_t o_q2   = alloc(C2_ * 4);
  size_t o_socC = alloc(B_ * 4);
  size_t o_socS = alloc(B_ * 4);
  size_t o_socF = alloc(B_ * 4);
  size_t o_socL = alloc(B_ * 4);
  size_t zeroEnd = off;                            // everything above zero-initialized
  size_t o_part = alloc((size_t)B_ * NCHUNK_ * C2_ * 4);   // 1 MB
  size_t o_tidx = alloc((size_t)NPOS_ * 4);
  size_t o_G    = alloc((size_t)3 * VP_ * C1_ * 4);
  size_t o_Z1   = alloc((size_t)TPAD_ * C1_ * 2);
  size_t o_Wr2  = alloc((size_t)384 * 256 * 2);
  size_t o_W3r  = alloc((size_t)128 * 384 * 2);
  size_t o_H    = alloc((size_t)TPAD_ * 384 * 2);
  size_t o_y2   = alloc((size_t)NPOS_ * C2_ * 2);  // 64 MB
  (void)ws_size; (void)n_in; (void)in_sizes; (void)out_size;

  int*            cnt  = (int*)(w + o_cnt);
  float*          m1a  = (float*)(w + o_m1);
  float*          v1a  = (float*)(w + o_v1);
  float*          s2a  = (float*)(w + o_s2);
  float*          q2a  = (float*)(w + o_q2);
  int*            socC = (int*)(w + o_socC);
  int*            socS = (int*)(w + o_socS);
  int*            socF = (int*)(w + o_socF);
  int*            socL = (int*)(w + o_socL);
  float*          part = (float*)(w + o_part);
  int*            tIdx = (int*)(w + o_tidx);
  float*          G    = (float*)(w + o_G);
  unsigned short* Z1   = (unsigned short*)(w + o_Z1);
  unsigned short* Wr2  = (unsigned short*)(w + o_Wr2);
  unsigned short* W3r  = (unsigned short*)(w + o_W3r);
  unsigned short* H    = (unsigned short*)(w + o_H);
  unsigned short* y2   = (unsigned short*)(w + o_y2);

  hipMemsetAsync(w, 0, zeroEnd, stream);

  k_prep       <<<66 + 768, 256, 0, stream>>>(W1, emb, W2, W3, G, Wr2, W3r);
  k_tidx_social<<<NPOS_ / 256, 256, 0, stream>>>(ids, tIdx, cnt, socC, socS, socF, socL);
  k_stats1     <<<(T_ + 15) / 16, 256, 0, stream>>>(G, b1, cnt, m1a, v1a);
  k_z1         <<<TPAD_ / 2, 256, 0, stream>>>(G, b1, m1a, v1a, g1, be1, (unsigned*)Z1);
  k_hgemm      <<<dim3((TPAD_ / 16 + 3) / 4, 3), 256, 0, stream>>>(Z1, Wr2, H);
  k_y2stats    <<<NPOS_ / YPB, 256, 0, stream>>>(tIdx, H, b2, y2, s2a, q2a);
  k_conv3      <<<B_ * NCHUNK_, 256, 0, stream>>>(y2, s2a, q2a, g2, be2, W3r, b3, part);
  k_final      <<<B_, 128, 0, stream>>>(part, socC, socS, socF, socL, bas, Ws, bs, Wo, bo, out);
}

// Round 9
// 266.566 us; speedup vs baseline: 1.2596x; 1.2596x over previous
//
#include <hip/hip_runtime.h>
#include <hip/hip_bf16.h>
#include <cstdint>
#include <cstddef>

// ---------------- problem constants ----------------
#define B_    32
#define S_    8192
#define D_    128
#define V_    21
#define VP_   22                 // vocab + zero-pad token (id 21 -> zero embedding row)
#define T_    (VP_*VP_*VP_)      // 10648 triples
#define TPAD_ 10656              // padded to multiple of 16 for MFMA tiles
#define C1_   256
#define C2_   128
#define NPOS_ (B_*S_)            // 262144
#define CH_   128                // conv3 positions per block
#define NCHUNK_ 64               // S_/CH_

using bf16x8 = __attribute__((ext_vector_type(8))) short;
using f32x4  = __attribute__((ext_vector_type(4))) float;
using u32x4  = __attribute__((ext_vector_type(4))) unsigned;

__device__ inline unsigned short f2bf(float f) {
  union { float f; unsigned u; } v; v.f = f;
  unsigned r = v.u + 0x7fffu + ((v.u >> 16) & 1u);
  return (unsigned short)(r >> 16);
}
__device__ inline float bf2f(unsigned short h) {
  union { unsigned u; float f; } v; v.u = ((unsigned)h) << 16; return v.f;
}

// ---------------- K1: G build + weight transposes + tidx/social (merged) ----------
// bid<66: G ; 66..833: weight transpose ; >=834: tidx + histogram + social partials
__global__ void k_prep(const float* __restrict__ W1, const float* __restrict__ emb,
                       const float* __restrict__ W2, const float* __restrict__ W3,
                       float* __restrict__ G, unsigned short* __restrict__ Wr2,
                       unsigned short* __restrict__ W3r,
                       const int* __restrict__ ids, int* __restrict__ tIdx,
                       int* __restrict__ cnt, int* __restrict__ socC,
                       int* __restrict__ socS, int* __restrict__ socF,
                       int* __restrict__ socL) {
  int bid = blockIdx.x;
  if (bid < 66) {
    int v = bid % VP_, k = bid / VP_, o = threadIdx.x;   // block 256
    __shared__ float e[D_];
    if (o < D_) e[o] = (v < V_) ? emb[v * D_ + o] : 0.f;
    __syncthreads();
    float acc = 0.f;
    if (v < V_) {
      for (int i = 0; i < D_; ++i) acc += W1[o * (D_ * 3) + i * 3 + k] * e[i];
    }
    G[(k * VP_ + v) * C1_ + o] = acc;
    return;
  }
  if (bid < 834) {
    int idx = (bid - 66) * 256 + threadIdx.x;
    if (idx < 384 * 256) {
      int r = idx >> 8, o = idx & 255;
      int k = r >> 7, p = r & 127;
      Wr2[idx] = f2bf(W2[(p * C1_ + o) * 3 + k]);
    } else {
      int j = idx - 384 * 256;
      if (j < 128 * 384) {
        int q = j / 384, kk = j % 384;
        int k = kk >> 7, p = kk & 127;
        W3r[q * 384 + kk] = f2bf(W3[(q * C2_ + p) * 3 + k]);
      }
    }
    return;
  }
  // ---- tidx + social ----
  int idx = (bid - 834) * 256 + threadIdx.x;
  int b = idx >> 13, s = idx & (S_ - 1);
  const int* row = ids + b * S_;
  int a = (s > 0)      ? row[s - 1] : V_;
  int m = row[s];
  int c = (s < S_ - 1) ? row[s + 1] : V_;
  int t = (a * VP_ + m) * VP_ + c;
  tIdx[idx] = t;
  atomicAdd(&cnt[t], 1);

  bool sm = (m == 1) | (m == 18);
  bool pm = (a == 1) | (a == 18);          // s==0 -> a==V_ -> false (matches ref)
  unsigned long long bm = __ballot(sm);
  unsigned long long bs = __ballot(sm && !pm);
  __shared__ int l0, l1, l2, l3;
  if (threadIdx.x == 0) { l0 = 0; l1 = 0; l2 = 0; l3 = 0; }
  __syncthreads();
  int lane = threadIdx.x & 63;
  // first/last: encode first as max(S-1-s) so zero-init works
  int fc = sm ? (S_ - 1 - s) : 0;
  int lv = sm ? s : 0;
#pragma unroll
  for (int off = 1; off < 64; off <<= 1) {
    fc = max(fc, __shfl_xor(fc, off));
    lv = max(lv, __shfl_xor(lv, off));
  }
  if (lane == 0) {
    atomicAdd(&l0, (int)__popcll(bm));
    atomicAdd(&l1, (int)__popcll(bs));
    atomicMax(&l2, fc);
    atomicMax(&l3, lv);
  }
  __syncthreads();
  if (threadIdx.x == 0) {
    atomicAdd(&socC[b], l0); atomicAdd(&socS[b], l1);
    atomicMax(&socF[b], l2); atomicMax(&socL[b], l3);
  }
}

// ---------------- K4: BN1 stats only (weighted by histogram) ----------
__global__ void k_stats1(const float* __restrict__ G, const float* __restrict__ b1,
                         const int* __restrict__ cnt,
                         float* __restrict__ m1acc, float* __restrict__ v1acc) {
  int o = threadIdx.x;   // 256
  float bb = b1[o];
  float s = 0.f, sq = 0.f;
  int t0 = blockIdx.x * 16;
#pragma unroll 4
  for (int i = 0; i < 16; ++i) {
    int t = t0 + i;
    if (t >= T_) break;
    int a = t / (VP_ * VP_), m = (t / VP_) % VP_, c = t % VP_;
    float x = G[a * C1_ + o] + G[(VP_ + m) * C1_ + o] + G[(2 * VP_ + c) * C1_ + o] + bb;
    float w = (float)cnt[t];
    s += w * x; sq += w * x * x;
  }
  atomicAdd(&m1acc[o], s);
  atomicAdd(&v1acc[o], sq);
}

// ---------------- K7: Z1[t] = bf16(relu(bn1(G-sum))), recomputed from G ----------
__global__ void k_z1(const float* __restrict__ G, const float* __restrict__ b1,
                     const float* __restrict__ m1a, const float* __restrict__ v1a,
                     const float* __restrict__ g1, const float* __restrict__ be1,
                     unsigned* __restrict__ Z1u) {
  int tid = threadIdx.x;
  int t = blockIdx.x * 2 + (tid >> 7);
  int o = (tid & 127) * 2;
  float m0 = m1a[o] * (1.f / NPOS_), m1v = m1a[o + 1] * (1.f / NPOS_);
  float a0 = g1[o]     * rsqrtf(v1a[o]     * (1.f / NPOS_) - m0 * m0   + 1e-5f);
  float a1 = g1[o + 1] * rsqrtf(v1a[o + 1] * (1.f / NPOS_) - m1v * m1v + 1e-5f);
  float c0 = be1[o] - m0 * a0, c1 = be1[o + 1] - m1v * a1;
  unsigned pk = 0;
  if (t < T_) {
    int a = t / (VP_ * VP_), m = (t / VP_) % VP_, c = t % VP_;
    float2 xa = *(const float2*)(G + (size_t)a * C1_ + o);
    float2 xm = *(const float2*)(G + (size_t)(VP_ + m) * C1_ + o);
    float2 xc = *(const float2*)(G + (size_t)(2 * VP_ + c) * C1_ + o);
    float x0 = xa.x + xm.x + xc.x + b1[o];
    float x1 = xa.y + xm.y + xc.y + b1[o + 1];
    float z0 = fmaxf(a0 * x0 + c0, 0.f);
    float z1 = fmaxf(a1 * x1 + c1, 0.f);
    pk = (unsigned)f2bf(z0) | ((unsigned)f2bf(z1) << 16);
  }
  Z1u[(size_t)t * 128 + (tid & 127)] = pk;
}

// ---------------- K9: H GEMM  H[t][r] = sum_o Z1[t][o]*Wr2[r][o]  (bf16 MFMA) ----
__global__ void __launch_bounds__(256) k_hgemm(const unsigned short* __restrict__ Z1,
                                               const unsigned short* __restrict__ Wr2,
                                               unsigned short* __restrict__ H) {
  int wave = threadIdx.x >> 6, lane = threadIdx.x & 63;
  int mt = blockIdx.x * 4 + wave;                 // m-tile (16 t-rows)
  if (mt >= TPAD_ / 16) return;
  int nt0 = blockIdx.y * 8;
  int rc   = lane & 15;                            // A-row / B-col / D-col
  int kgrp = lane >> 4;                            // k-offset group
  bf16x8 af[8];
  const unsigned short* Arow = Z1 + (size_t)(mt * 16 + rc) * C1_ + kgrp * 8;
#pragma unroll
  for (int st = 0; st < 8; ++st) af[st] = *(const bf16x8*)(Arow + st * 32);
#pragma unroll
  for (int ntp = 0; ntp < 4; ++ntp) {
    int ntA = nt0 + ntp * 2, ntB = ntA + 1;
    f32x4 accA = {0.f, 0.f, 0.f, 0.f}, accB = {0.f, 0.f, 0.f, 0.f};
    const unsigned short* BrA = Wr2 + (size_t)(ntA * 16 + rc) * C1_ + kgrp * 8;
    const unsigned short* BrB = Wr2 + (size_t)(ntB * 16 + rc) * C1_ + kgrp * 8;
#pragma unroll
    for (int st = 0; st < 8; ++st) {
      bf16x8 bA = *(const bf16x8*)(BrA + st * 32);
      bf16x8 bB = *(const bf16x8*)(BrB + st * 32);
      accA = __builtin_amdgcn_mfma_f32_16x16x32_bf16(af[st], bA, accA, 0, 0, 0);
      accB = __builtin_amdgcn_mfma_f32_16x16x32_bf16(af[st], bB, accB, 0, 0, 0);
    }
#pragma unroll
    for (int r = 0; r < 4; ++r) {
      int m = mt * 16 + kgrp * 4 + r;              // D row
      H[(size_t)m * 384 + ntA * 16 + rc] = f2bf(accA[r]);
      H[(size_t)m * 384 + ntB * 16 + rc] = f2bf(accB[r]);
    }
  }
}

// ---------------- K10: y2 gather (ONCE) + BN2 stats + y2 store ----------------
#define YPB 256
__global__ void __launch_bounds__(256, 3) k_y2stats(const int* __restrict__ tIdx,
        const unsigned short* __restrict__ H, const float* __restrict__ b2,
        unsigned short* __restrict__ y2, float* __restrict__ sum, float* __restrict__ sq) {
  int lane16 = threadIdx.x & 15;       // channel slice: ch = lane16*8 .. +8
  int pgrp   = threadIdx.x >> 4;       // 0..15
  int base0  = blockIdx.x * YPB;
  float bb[8];
  const float* b2s = b2 + lane16 * 8;
#pragma unroll
  for (int j = 0; j < 8; ++j) bb[j] = b2s[j];
  float sAcc[8] = {0,0,0,0,0,0,0,0}, qAcc[8] = {0,0,0,0,0,0,0,0};

  for (int ib = 0; ib < 2; ++ib) {
    int base = base0 + ib * 128;
    int tA[8], tM[8], tC[8];
#pragma unroll
    for (int i = 0; i < 8; ++i) {
      int pos = base + i * 16 + pgrp;
      int s = pos & (S_ - 1);
      const int* tr = tIdx + (pos & ~(S_ - 1));
      tM[i] = tr[s];
      int sa = s > 0 ? s - 1 : 0;
      int sc = s < S_ - 1 ? s + 1 : s;
      int ta = tr[sa], tc = tr[sc];
      tA[i] = (s > 0)      ? ta : T_;
      tC[i] = (s < S_ - 1) ? tc : T_;
    }
    bf16x8 h0[8], h1[8], h2[8];
#pragma unroll
    for (int i = 0; i < 8; ++i)
      h1[i] = *(const bf16x8*)(H + (size_t)tM[i] * 384 + 128 + lane16 * 8);
#pragma unroll
    for (int i = 0; i < 8; ++i)
      h0[i] = *(const bf16x8*)(H + (size_t)tA[i] * 384 +   0 + lane16 * 8);
#pragma unroll
    for (int i = 0; i < 8; ++i)
      h2[i] = *(const bf16x8*)(H + (size_t)tC[i] * 384 + 256 + lane16 * 8);

#pragma unroll
    for (int i = 0; i < 8; ++i) {
      int pos = base + i * 16 + pgrp;
      float y[8];
#pragma unroll
      for (int j = 0; j < 8; ++j) {
        y[j] = bb[j] + bf2f((unsigned short)h0[i][j]) + bf2f((unsigned short)h1[i][j])
                     + bf2f((unsigned short)h2[i][j]);
        sAcc[j] += y[j]; qAcc[j] += y[j] * y[j];
      }
      u32x4 pk;
      pk[0] = (unsigned)f2bf(y[0]) | ((unsigned)f2bf(y[1]) << 16);
      pk[1] = (unsigned)f2bf(y[2]) | ((unsigned)f2bf(y[3]) << 16);
      pk[2] = (unsigned)f2bf(y[4]) | ((unsigned)f2bf(y[5]) << 16);
      pk[3] = (unsigned)f2bf(y[6]) | ((unsigned)f2bf(y[7]) << 16);
      *(u32x4*)(y2 + (size_t)pos * C2_ + lane16 * 8) = pk;
    }
  }

  __shared__ float ls[128], lq[128];
  if (threadIdx.x < 128) { ls[threadIdx.x] = 0.f; lq[threadIdx.x] = 0.f; }
  __syncthreads();
  int lane = threadIdx.x & 63;
#pragma unroll
  for (int j = 0; j < 8; ++j) {
    float v = sAcc[j], q = qAcc[j];
    v += __shfl_xor(v, 16); v += __shfl_xor(v, 32);
    q += __shfl_xor(q, 16); q += __shfl_xor(q, 32);
    if (lane < 16) { atomicAdd(&ls[lane16 * 8 + j], v); atomicAdd(&lq[lane16 * 8 + j], q); }
  }
  __syncthreads();
  if (threadIdx.x < 128) {
    atomicAdd(&sum[threadIdx.x], ls[threadIdx.x]);
    atomicAdd(&sq[threadIdx.x],  lq[threadIdx.x]);
  }
}

// ---------------- K12: conv3 — ZERO global loads in the MFMA loop ----------------
// 256 thr (4 waves), CH=128. Wave w owns q in [w*32, w*32+32) x all 8 pos-tiles.
// A-fragments batch-preloaded to regs per kh-half (12 x 16B); B from swizzled LDS,
// each ds_read feeds 2 MFMAs. Per-wave epilogue (disjoint q), no cross-wave reduce.
__global__ void __launch_bounds__(256, 3) k_conv3(const unsigned short* __restrict__ y2,
      const float* __restrict__ s2a, const float* __restrict__ q2a,
      const float* __restrict__ g2, const float* __restrict__ be2,
      const unsigned short* __restrict__ W3r, const float* __restrict__ b3,
      float* __restrict__ part) {
  __shared__ unsigned short z2s[130 * 128];       // 33280 B
  int b     = blockIdx.x >> 6;                    // NCHUNK_=64 chunks per batch row
  int chunk = blockIdx.x & 63;
  int s0    = chunk * CH_;
  int tid = threadIdx.x;

  // ---- phase 1: stream y2 rows s0-1 .. s0+128, bn2(inline)+relu, swizzled LDS store ----
  {
    int lane16 = tid & 15;           // 8-channel slice
    int rowg   = tid >> 4;           // 0..15
    const unsigned short* ybase = y2 + (size_t)b * S_ * C2_ + lane16 * 8;
    bf16x8 hv[9];
    int uu[9];
#pragma unroll
    for (int it = 0; it < 9; ++it) {
      int pos = it * 16 + rowg;
      int u = s0 - 1 + pos;
      uu[it] = u;
      int uc = min(max(u, 0), S_ - 1);
      hv[it] = *(const bf16x8*)(ybase + (size_t)uc * C2_);
    }
    float aa[8], cc[8];
#pragma unroll
    for (int j = 0; j < 8; ++j) {
      int ch = lane16 * 8 + j;
      float mm = s2a[ch] * (1.f / NPOS_);
      float vv = q2a[ch] * (1.f / NPOS_) - mm * mm;
      float a  = g2[ch] * rsqrtf(vv + 1e-5f);
      aa[j] = a; cc[j] = be2[ch] - mm * a;
    }
#pragma unroll
    for (int it = 0; it < 9; ++it) {
      int pos = it * 16 + rowg;
      bool valid = (uu[it] >= 0) & (uu[it] < S_);
      float z[8];
#pragma unroll
      for (int j = 0; j < 8; ++j)
        z[j] = fmaxf(aa[j] * bf2f((unsigned short)hv[it][j]) + cc[j], 0.f);
      u32x4 pk;
      pk[0] = (unsigned)f2bf(z[0]) | ((unsigned)f2bf(z[1]) << 16);
      pk[1] = (unsigned)f2bf(z[2]) | ((unsigned)f2bf(z[3]) << 16);
      pk[2] = (unsigned)f2bf(z[4]) | ((unsigned)f2bf(z[5]) << 16);
      pk[3] = (unsigned)f2bf(z[6]) | ((unsigned)f2bf(z[7]) << 16);
      if (!valid) pk = (u32x4){0, 0, 0, 0};
      if (pos < CH_ + 2) {
        int byte = (lane16 * 16) ^ ((pos & 15) << 4);   // 4-bit XOR swizzle
        *(u32x4*)((char*)z2s + pos * 256 + byte) = pk;
      }
    }
  }
  __syncthreads();

  // ---- phase 2: MFMA. A preloaded per kh-half; B from LDS only ----
  int wave = tid >> 6, lane = tid & 63;
  int rc = lane & 15, kgrp = lane >> 4;
  int q0 = wave * 32;
  f32x4 acc[2][8];
#pragma unroll
  for (int qt = 0; qt < 2; ++qt)
#pragma unroll
    for (int nt = 0; nt < 8; ++nt) acc[qt][nt] = (f32x4){0.f, 0.f, 0.f, 0.f};

  const unsigned short* A0 = W3r + (size_t)(q0 +  0 + rc) * 384 + kgrp * 8;
  const unsigned short* A1 = W3r + (size_t)(q0 + 16 + rc) * 384 + kgrp * 8;
#pragma unroll
  for (int kh = 0; kh < 2; ++kh) {
    bf16x8 af0[6], af1[6];
#pragma unroll
    for (int s6 = 0; s6 < 6; ++s6) {
      af0[s6] = *(const bf16x8*)(A0 + (kh * 6 + s6) * 32);
      af1[s6] = *(const bf16x8*)(A1 + (kh * 6 + s6) * 32);
    }
#pragma unroll
    for (int s6 = 0; s6 < 6; ++s6) {
      int st = kh * 6 + s6;
      int k = st >> 2, pb = st & 3;
      int pbyte = pb * 64 + kgrp * 16;
#pragma unroll
      for (int nt = 0; nt < 8; ++nt) {
        int pos  = nt * 16 + rc + k;
        bf16x8 bfr = *(const bf16x8*)((const char*)z2s + pos * 256 + (pbyte ^ ((pos & 15) << 4)));
        acc[0][nt] = __builtin_amdgcn_mfma_f32_16x16x32_bf16(af0[s6], bfr, acc[0][nt], 0, 0, 0);
        acc[1][nt] = __builtin_amdgcn_mfma_f32_16x16x32_bf16(af1[s6], bfr, acc[1][nt], 0, 0, 0);
      }
    }
  }

  // ---- epilogue: +b3, ReLU, sum over 128 pos (8 tiles + shfl over rc), store ----
#pragma unroll
  for (int qt = 0; qt < 2; ++qt) {
    float p[4];
    const float4 b3q = *(const float4*)(b3 + q0 + qt * 16 + kgrp * 4);
#pragma unroll
    for (int r = 0; r < 4; ++r) p[r] = 0.f;
#pragma unroll
    for (int nt = 0; nt < 8; ++nt) {
      p[0] += fmaxf(acc[qt][nt][0] + b3q.x, 0.f);
      p[1] += fmaxf(acc[qt][nt][1] + b3q.y, 0.f);
      p[2] += fmaxf(acc[qt][nt][2] + b3q.z, 0.f);
      p[3] += fmaxf(acc[qt][nt][3] + b3q.w, 0.f);
    }
#pragma unroll
    for (int off = 1; off < 16; off <<= 1) {
      p[0] += __shfl_xor(p[0], off); p[1] += __shfl_xor(p[1], off);
      p[2] += __shfl_xor(p[2], off); p[3] += __shfl_xor(p[3], off);
    }
    if (rc == 0) {
      float* dst = part + ((size_t)b * NCHUNK_ + chunk) * C2_ + q0 + qt * 16 + kgrp * 4;
      dst[0] = p[0]; dst[1] = p[1]; dst[2] = p[2]; dst[3] = p[3];
    }
  }
}

// ---------------- K14: partial reduce + social finalize + output GEMV ----------------
__global__ void k_final(const float* __restrict__ part,
      const int* __restrict__ socC, const int* __restrict__ socS,
      const int* __restrict__ socF, const int* __restrict__ socL,
      const float* __restrict__ baseline,
      const float* __restrict__ Ws, const float* __restrict__ bs,
      const float* __restrict__ Wo, const float* __restrict__ bo,
      float* __restrict__ out) {
  int b = blockIdx.x, q = threadIdx.x;             // 128 threads
  __shared__ float h[256];
  __shared__ float st3[3];
  {
    float acc = 0.f;
    const float* pb = part + (size_t)b * NCHUNK_ * C2_ + q;
#pragma unroll 8
    for (int i = 0; i < NCHUNK_; ++i) acc += pb[i * C2_];
    h[q] = acc * (1.f / S_);
  }
  if (q == 0) {
    float total = (float)socC[b], nseg = (float)socS[b];
    int first = (S_ - 1) - socF[b], last = socL[b];
    float mu   = (nseg > 0.f) ? total / fmaxf(nseg, 1.f) : 0.f;
    float gap  = (nseg > 0.f) ? (float)(last - first + 1) - total : 0.f;
    float resp = (nseg > 1.f) ? gap / fmaxf(nseg - 1.f, 1.f) : 0.f;
    st3[0] = mu; st3[1] = nseg; st3[2] = resp;
    float den = baseline[b * 3 + 0] * baseline[b * 3 + 1] + 1e-10f;
    float sws = 1.f - mu * nseg / den;
    out[B_ * C2_ + b] = fminf(fmaxf(sws, 0.f), 1.f);
  }
  __syncthreads();
  h[128 + q] = Ws[q * 3] * st3[0] + Ws[q * 3 + 1] * st3[1] + Ws[q * 3 + 2] * st3[2] + bs[q];
  __syncthreads();
  float acc = bo[q];
  const float4* Wo4 = (const float4*)(Wo + q * 256);
#pragma unroll 8
  for (int j4 = 0; j4 < 64; ++j4) {
    float4 wv = Wo4[j4];
    acc += wv.x * h[j4 * 4] + wv.y * h[j4 * 4 + 1] + wv.z * h[j4 * 4 + 2] + wv.w * h[j4 * 4 + 3];
  }
  out[b * C2_ + q] = acc;
}

// ---------------- launch ----------------
extern "C" void kernel_launch(void* const* d_in, const int* in_sizes, int n_in,
                              void* d_out, int out_size, void* d_ws, size_t ws_size,
                              hipStream_t stream) {
  const int*   ids = (const int*)  d_in[0];
  const float* bas = (const float*)d_in[1];
  const float* emb = (const float*)d_in[2];
  const float* W1  = (const float*)d_in[3];
  const float* b1  = (const float*)d_in[4];
  const float* g1  = (const float*)d_in[5];
  const float* be1 = (const float*)d_in[6];
  const float* W2  = (const float*)d_in[7];
  const float* b2  = (const float*)d_in[8];
  const float* g2  = (const float*)d_in[9];
  const float* be2 = (const float*)d_in[10];
  const float* W3  = (const float*)d_in[11];
  const float* b3  = (const float*)d_in[12];
  const float* Ws  = (const float*)d_in[13];
  const float* bs  = (const float*)d_in[14];
  const float* Wo  = (const float*)d_in[15];
  const float* bo  = (const float*)d_in[16];
  float* out = (float*)d_out;

  char* w = (char*)d_ws;
  size_t off = 0;
  auto alloc = [&](size_t bytes) -> size_t {
    size_t o = off; off = (off + bytes + 255) & ~(size_t)255; return o;
  };
  size_t o_cnt  = alloc(T_ * 4);
  size_t o_m1   = alloc(C1_ * 4);
  size_t o_v1   = alloc(C1_ * 4);
  size_t o_s2   = alloc(C2_ * 4);
  size_t o_q2   = alloc(C2_ * 4);
  size_t o_socC = alloc(B_ * 4);
  size_t o_socS = alloc(B_ * 4);
  size_t o_socF = alloc(B_ * 4);
  size_t o_socL = alloc(B_ * 4);
  size_t zeroEnd = off;                            // everything above zero-initialized
  size_t o_part = alloc((size_t)B_ * NCHUNK_ * C2_ * 4);   // 1 MB
  size_t o_tidx = alloc((size_t)NPOS_ * 4);
  size_t o_G    = alloc((size_t)3 * VP_ * C1_ * 4);
  size_t o_Z1   = alloc((size_t)TPAD_ * C1_ * 2);
  size_t o_Wr2  = alloc((size_t)384 * 256 * 2);
  size_t o_W3r  = alloc((size_t)128 * 384 * 2);
  size_t o_H    = alloc((size_t)TPAD_ * 384 * 2);
  size_t o_y2   = alloc((size_t)NPOS_ * C2_ * 2);  // 64 MB
  (void)ws_size; (void)n_in; (void)in_sizes; (void)out_size;

  int*            cnt  = (int*)(w + o_cnt);
  float*          m1a  = (float*)(w + o_m1);
  float*          v1a  = (float*)(w + o_v1);
  float*          s2a  = (float*)(w + o_s2);
  float*          q2a  = (float*)(w + o_q2);
  int*            socC = (int*)(w + o_socC);
  int*            socS = (int*)(w + o_socS);
  int*            socF = (int*)(w + o_socF);
  int*            socL = (int*)(w + o_socL);
  float*          part = (float*)(w + o_part);
  int*            tIdx = (int*)(w + o_tidx);
  float*          G    = (float*)(w + o_G);
  unsigned short* Z1   = (unsigned short*)(w + o_Z1);
  unsigned short* Wr2  = (unsigned short*)(w + o_Wr2);
  unsigned short* W3r  = (unsigned short*)(w + o_W3r);
  unsigned short* H    = (unsigned short*)(w + o_H);
  unsigned short* y2   = (unsigned short*)(w + o_y2);

  hipMemsetAsync(w, 0, zeroEnd, stream);

  k_prep    <<<834 + NPOS_ / 256, 256, 0, stream>>>(W1, emb, W2, W3, G, Wr2, W3r,
                                                    ids, tIdx, cnt, socC, socS, socF, socL);
  k_stats1  <<<(T_ + 15) / 16, 256, 0, stream>>>(G, b1, cnt, m1a, v1a);
  k_z1      <<<TPAD_ / 2, 256, 0, stream>>>(G, b1, m1a, v1a, g1, be1, (unsigned*)Z1);
  k_hgemm   <<<dim3((TPAD_ / 16 + 3) / 4, 3), 256, 0, stream>>>(Z1, Wr2, H);
  k_y2stats <<<NPOS_ / YPB, 256, 0, stream>>>(tIdx, H, b2, y2, s2a, q2a);
  k_conv3   <<<B_ * NCHUNK_, 256, 0, stream>>>(y2, s2a, q2a, g2, be2, W3r, b3, part);
  k_final   <<<B_, 128, 0, stream>>>(part, socC, socS, socF, socL, bas, Ws, bs, Wo, bo, out);
}

// Round 12
// 249.819 us; speedup vs baseline: 1.3440x; 1.0670x over previous
//
#include <hip/hip_runtime.h>
#include <hip/hip_bf16.h>
#include <cstdint>
#include <cstddef>

// ---------------- problem constants ----------------
#define B_    32
#define S_    8192
#define D_    128
#define V_    21
#define VP_   22                 // vocab + zero-pad token (id 21 -> zero embedding row)
#define T_    (VP_*VP_*VP_)      // 10648 triples
#define TPAD_ 10656              // padded to multiple of 16 for MFMA tiles
#define C1_   256
#define C2_   128
#define NPOS_ (B_*S_)            // 262144
#define CH_   128                // conv3 positions per block
#define NCHUNK_ 64               // S_/CH_
#define NSET_ 32                 // bn2 partial accumulator sets

using bf16x8 = __attribute__((ext_vector_type(8))) short;
using f32x4  = __attribute__((ext_vector_type(4))) float;
using u32x4  = __attribute__((ext_vector_type(4))) unsigned;

__device__ inline unsigned short f2bf(float f) {
  union { float f; unsigned u; } v; v.f = f;
  unsigned r = v.u + 0x7fffu + ((v.u >> 16) & 1u);
  return (unsigned short)(r >> 16);
}
__device__ inline float bf2f(unsigned short h) {
  union { unsigned u; float f; } v; v.u = ((unsigned)h) << 16; return v.f;
}

// ---------------- K1: G build + weight transposes + tidx/social (merged) ----------
__global__ void k_prep(const float* __restrict__ W1, const float* __restrict__ emb,
                       const float* __restrict__ W2, const float* __restrict__ W3,
                       float* __restrict__ G, unsigned short* __restrict__ Wr2,
                       unsigned short* __restrict__ W3r,
                       const int* __restrict__ ids, int* __restrict__ tIdx,
                       int* __restrict__ cnt, int* __restrict__ socC,
                       int* __restrict__ socS, int* __restrict__ socF,
                       int* __restrict__ socL) {
  int bid = blockIdx.x;
  if (bid < 66) {
    int v = bid % VP_, k = bid / VP_, o = threadIdx.x;   // block 256
    __shared__ float e[D_];
    if (o < D_) e[o] = (v < V_) ? emb[v * D_ + o] : 0.f;
    __syncthreads();
    float acc = 0.f;
    if (v < V_) {
      for (int i = 0; i < D_; ++i) acc += W1[o * (D_ * 3) + i * 3 + k] * e[i];
    }
    G[(k * VP_ + v) * C1_ + o] = acc;
    return;
  }
  if (bid < 834) {
    int idx = (bid - 66) * 256 + threadIdx.x;
    if (idx < 384 * 256) {
      int r = idx >> 8, o = idx & 255;
      int k = r >> 7, p = r & 127;
      Wr2[idx] = f2bf(W2[(p * C1_ + o) * 3 + k]);
    } else {
      int j = idx - 384 * 256;
      if (j < 128 * 384) {
        int q = j / 384, kk = j % 384;
        int k = kk >> 7, p = kk & 127;
        W3r[q * 384 + kk] = f2bf(W3[(q * C2_ + p) * 3 + k]);
      }
    }
    return;
  }
  // ---- tidx + social ----
  int idx = (bid - 834) * 256 + threadIdx.x;
  int b = idx >> 13, s = idx & (S_ - 1);
  const int* row = ids + b * S_;
  int a = (s > 0)      ? row[s - 1] : V_;
  int m = row[s];
  int c = (s < S_ - 1) ? row[s + 1] : V_;
  int t = (a * VP_ + m) * VP_ + c;
  tIdx[idx] = t;
  atomicAdd(&cnt[t], 1);

  bool sm = (m == 1) | (m == 18);
  bool pm = (a == 1) | (a == 18);          // s==0 -> a==V_ -> false (matches ref)
  unsigned long long bm = __ballot(sm);
  unsigned long long bs = __ballot(sm && !pm);
  __shared__ int l0, l1, l2, l3;
  if (threadIdx.x == 0) { l0 = 0; l1 = 0; l2 = 0; l3 = 0; }
  __syncthreads();
  int lane = threadIdx.x & 63;
  // first/last: encode first as max(S-1-s) so zero-init works
  int fc = sm ? (S_ - 1 - s) : 0;
  int lv = sm ? s : 0;
#pragma unroll
  for (int off = 1; off < 64; off <<= 1) {
    fc = max(fc, __shfl_xor(fc, off));
    lv = max(lv, __shfl_xor(lv, off));
  }
  if (lane == 0) {
    atomicAdd(&l0, (int)__popcll(bm));
    atomicAdd(&l1, (int)__popcll(bs));
    atomicMax(&l2, fc);
    atomicMax(&l3, lv);
  }
  __syncthreads();
  if (threadIdx.x == 0) {
    atomicAdd(&socC[b], l0); atomicAdd(&socS[b], l1);
    atomicMax(&socF[b], l2); atomicMax(&socL[b], l3);
  }
}

// ---------------- K2: BN1 stats (bias cancels in BN) + last-block a1/c1 ----------
__global__ void k_stats1(const float* __restrict__ G, const int* __restrict__ cnt,
                         const float* __restrict__ g1, const float* __restrict__ be1,
                         float* __restrict__ m1acc, float* __restrict__ v1acc,
                         int* __restrict__ done, float* __restrict__ a1,
                         float* __restrict__ c1) {
  int o = threadIdx.x;   // 256
  float s = 0.f, sq = 0.f;
  int t0 = blockIdx.x * 64;
#pragma unroll 4
  for (int i = 0; i < 64; ++i) {
    int t = t0 + i;
    if (t < T_) {
      int a = t / (VP_ * VP_), m = (t / VP_) % VP_, c = t % VP_;
      float x = G[a * C1_ + o] + G[(VP_ + m) * C1_ + o] + G[(2 * VP_ + c) * C1_ + o];
      float wgt = (float)cnt[t];
      s += wgt * x; sq += wgt * x * x;
    }
  }
  atomicAdd(&m1acc[o], s);
  atomicAdd(&v1acc[o], sq);
  __syncthreads();                 // drains vmcnt -> our atomics are globally visible
  __shared__ int lastFlag;
  if (o == 0) lastFlag = (atomicAdd(done, 1) == (int)gridDim.x - 1);
  __syncthreads();
  if (lastFlag) {
    float ms = atomicAdd(&m1acc[o], 0.f);     // atomic read (coherent)
    float vs = atomicAdd(&v1acc[o], 0.f);
    float mu  = ms * (1.f / NPOS_);
    float var = vs * (1.f / NPOS_) - mu * mu;
    float a   = g1[o] * rsqrtf(var + 1e-5f);
    a1[o] = a; c1[o] = be1[o] - mu * a;
  }
}

// ---------------- K3: H GEMM with z1 fused (A computed from G + bn1) ----------
__global__ void __launch_bounds__(256) k_hgemm(const float* __restrict__ G,
      const float* __restrict__ a1, const float* __restrict__ c1,
      const unsigned short* __restrict__ Wr2, unsigned short* __restrict__ H) {
  int wave = threadIdx.x >> 6, lane = threadIdx.x & 63;
  int mt = blockIdx.x * 4 + wave;                 // m-tile (16 t-rows)
  if (mt >= TPAD_ / 16) return;
  int nt0 = blockIdx.y * 8;
  int rc   = lane & 15;
  int kgrp = lane >> 4;
  int t = mt * 16 + rc;
  bf16x8 af[8];
  if (t < T_) {
    int a = t / (VP_ * VP_), m = (t / VP_) % VP_, c = t % VP_;
    const float* Ga = G + (size_t)a * C1_;
    const float* Gm = G + (size_t)(VP_ + m) * C1_;
    const float* Gc = G + (size_t)(2 * VP_ + c) * C1_;
#pragma unroll
    for (int st = 0; st < 8; ++st) {
      int o0 = kgrp * 8 + st * 32;
#pragma unroll
      for (int j4 = 0; j4 < 2; ++j4) {
        float4 xa = *(const float4*)(Ga + o0 + j4 * 4);
        float4 xm = *(const float4*)(Gm + o0 + j4 * 4);
        float4 xc = *(const float4*)(Gc + o0 + j4 * 4);
        float4 av = *(const float4*)(a1 + o0 + j4 * 4);
        float4 cv = *(const float4*)(c1 + o0 + j4 * 4);
        af[st][j4 * 4 + 0] = (short)f2bf(fmaxf(av.x * (xa.x + xm.x + xc.x) + cv.x, 0.f));
        af[st][j4 * 4 + 1] = (short)f2bf(fmaxf(av.y * (xa.y + xm.y + xc.y) + cv.y, 0.f));
        af[st][j4 * 4 + 2] = (short)f2bf(fmaxf(av.z * (xa.z + xm.z + xc.z) + cv.z, 0.f));
        af[st][j4 * 4 + 3] = (short)f2bf(fmaxf(av.w * (xa.w + xm.w + xc.w) + cv.w, 0.f));
      }
    }
  } else {
#pragma unroll
    for (int st = 0; st < 8; ++st) af[st] = (bf16x8){0, 0, 0, 0, 0, 0, 0, 0};
  }
#pragma unroll
  for (int ntp = 0; ntp < 4; ++ntp) {
    int ntA = nt0 + ntp * 2, ntB = ntA + 1;
    f32x4 accA = {0.f, 0.f, 0.f, 0.f}, accB = {0.f, 0.f, 0.f, 0.f};
    const unsigned short* BrA = Wr2 + (size_t)(ntA * 16 + rc) * C1_ + kgrp * 8;
    const unsigned short* BrB = Wr2 + (size_t)(ntB * 16 + rc) * C1_ + kgrp * 8;
#pragma unroll
    for (int st = 0; st < 8; ++st) {
      bf16x8 bA = *(const bf16x8*)(BrA + st * 32);
      bf16x8 bB = *(const bf16x8*)(BrB + st * 32);
      accA = __builtin_amdgcn_mfma_f32_16x16x32_bf16(af[st], bA, accA, 0, 0, 0);
      accB = __builtin_amdgcn_mfma_f32_16x16x32_bf16(af[st], bB, accB, 0, 0, 0);
    }
#pragma unroll
    for (int r = 0; r < 4; ++r) {
      int mrow = mt * 16 + kgrp * 4 + r;
      H[(size_t)mrow * 384 + ntA * 16 + rc] = f2bf(accA[r]);
      H[(size_t)mrow * 384 + ntB * 16 + rc] = f2bf(accB[r]);
    }
  }
}

// ---------------- K4: BN2 stats — gather H, NO y2 store; 32-set atomics + last-block ----
__global__ void k_stats2(const int* __restrict__ tIdx, const unsigned short* __restrict__ H,
        float* __restrict__ s2p, float* __restrict__ q2p, int* __restrict__ done,
        const float* __restrict__ g2, const float* __restrict__ be2,
        float* __restrict__ a2, float* __restrict__ c2p) {
  int tid = threadIdx.x;
  int lane16 = tid & 15;       // channel slice: ch = lane16*8 .. +8
  int pgrp   = tid >> 4;       // 0..15
  int base   = blockIdx.x * 128;
  int tA[8], tM[8], tC[8];
#pragma unroll
  for (int i = 0; i < 8; ++i) {
    int pos = base + i * 16 + pgrp;
    int s = pos & (S_ - 1);
    const int* tr = tIdx + (pos & ~(S_ - 1));
    tM[i] = tr[s];
    int sa = s > 0 ? s - 1 : 0;
    int sc = s < S_ - 1 ? s + 1 : s;
    int ta = tr[sa], tc = tr[sc];
    tA[i] = (s > 0)      ? ta : T_;
    tC[i] = (s < S_ - 1) ? tc : T_;
  }
  bf16x8 h0[8], h1[8], h2[8];
#pragma unroll
  for (int i = 0; i < 8; ++i)
    h1[i] = *(const bf16x8*)(H + (size_t)tM[i] * 384 + 128 + lane16 * 8);
#pragma unroll
  for (int i = 0; i < 8; ++i)
    h0[i] = *(const bf16x8*)(H + (size_t)tA[i] * 384 +   0 + lane16 * 8);
#pragma unroll
  for (int i = 0; i < 8; ++i)
    h2[i] = *(const bf16x8*)(H + (size_t)tC[i] * 384 + 256 + lane16 * 8);

  float sAcc[8] = {0,0,0,0,0,0,0,0}, qAcc[8] = {0,0,0,0,0,0,0,0};
#pragma unroll
  for (int i = 0; i < 8; ++i) {
#pragma unroll
    for (int j = 0; j < 8; ++j) {
      float y = bf2f((unsigned short)h0[i][j]) + bf2f((unsigned short)h1[i][j])
              + bf2f((unsigned short)h2[i][j]);
      sAcc[j] += y; qAcc[j] += y * y;
    }
  }

  __shared__ float ls[128], lq[128];
  if (tid < 128) { ls[tid] = 0.f; lq[tid] = 0.f; }
  __syncthreads();
  int lane = tid & 63;
#pragma unroll
  for (int j = 0; j < 8; ++j) {
    float v = sAcc[j], q = qAcc[j];
    v += __shfl_xor(v, 16); v += __shfl_xor(v, 32);
    q += __shfl_xor(q, 16); q += __shfl_xor(q, 32);
    if (lane < 16) { atomicAdd(&ls[lane16 * 8 + j], v); atomicAdd(&lq[lane16 * 8 + j], q); }
  }
  __syncthreads();
  int set = (blockIdx.x & (NSET_ - 1)) * C2_;
  if (tid < 128) {
    atomicAdd(&s2p[set + tid], ls[tid]);
    atomicAdd(&q2p[set + tid], lq[tid]);
  }
  __syncthreads();                 // drains vmcnt -> atomics globally visible
  __shared__ int lastFlag;
  if (tid == 0) lastFlag = (atomicAdd(done, 1) == (int)gridDim.x - 1);
  __syncthreads();
  if (lastFlag && tid < 128) {
    float s = 0.f, q = 0.f;
    for (int k2 = 0; k2 < NSET_; ++k2) {
      s += atomicAdd(&s2p[k2 * C2_ + tid], 0.f);
      q += atomicAdd(&q2p[k2 * C2_ + tid], 0.f);
    }
    float mu  = s * (1.f / NPOS_);
    float var = q * (1.f / NPOS_) - mu * mu;
    float a   = g2[tid] * rsqrtf(var + 1e-5f);
    a2[tid] = a; c2p[tid] = be2[tid] - mu * a;   // bias b2 cancels in BN
  }
}

// ---------------- K5: conv3 — phase-1 gathers H directly (no y2) ----------------
// 256 thr (4 waves), CH=128. Phase 1: batched gather (max 15 loads in flight),
// z = relu(a2*hsum + c2'), swizzled LDS. Phase 2/epilogue: r9's proven structure.
__global__ void __launch_bounds__(256, 3) k_conv3(const int* __restrict__ tIdx,
      const unsigned short* __restrict__ H,
      const float* __restrict__ a2, const float* __restrict__ c2p,
      const unsigned short* __restrict__ W3r, const float* __restrict__ b3,
      float* __restrict__ part) {
  __shared__ unsigned short z2s[130 * 128];       // 33280 B
  int b     = blockIdx.x >> 6;                    // NCHUNK_=64 chunks per batch row
  int chunk = blockIdx.x & 63;
  int s0    = chunk * CH_;
  int tid = threadIdx.x;

  // ---- phase 1: gather H for positions s0-1 .. s0+128, bn2+relu, swizzled LDS ----
  {
    int lane16 = tid & 15;           // 8-channel slice
    int pgrp   = tid >> 4;           // 0..15
    const int* tr = tIdx + b * S_;
    float aa[8], cc[8];
#pragma unroll
    for (int j4 = 0; j4 < 2; ++j4) {
      float4 av = *(const float4*)(a2  + lane16 * 8 + j4 * 4);
      float4 cv = *(const float4*)(c2p + lane16 * 8 + j4 * 4);
      aa[j4 * 4 + 0] = av.x; aa[j4 * 4 + 1] = av.y;
      aa[j4 * 4 + 2] = av.z; aa[j4 * 4 + 3] = av.w;
      cc[j4 * 4 + 0] = cv.x; cc[j4 * 4 + 1] = cv.y;
      cc[j4 * 4 + 2] = cv.z; cc[j4 * 4 + 3] = cv.w;
    }
#pragma unroll
    for (int half = 0; half < 2; ++half) {
      const int i0 = half * 5;
      const int NB = half ? 4 : 5;     // 9x16=144 >= 130 positions
      int uu[5], iA[5], iM[5], iC[5];
#pragma unroll
      for (int i = 0; i < 5; ++i) {
        if (i >= NB) break;
        int pos = (i0 + i) * 16 + pgrp;
        int u = s0 - 1 + pos;
        int uc = min(max(u, 0), S_ - 1);
        uu[i] = u;
        iM[i] = tr[uc];
        iA[i] = (uc > 0)      ? tr[uc - 1] : T_;
        iC[i] = (uc < S_ - 1) ? tr[uc + 1] : T_;
      }
      bf16x8 h0[5], h1[5], h2[5];
#pragma unroll
      for (int i = 0; i < 5; ++i) {
        if (i >= NB) break;
        h1[i] = *(const bf16x8*)(H + (size_t)iM[i] * 384 + 128 + lane16 * 8);
      }
#pragma unroll
      for (int i = 0; i < 5; ++i) {
        if (i >= NB) break;
        h0[i] = *(const bf16x8*)(H + (size_t)iA[i] * 384 +   0 + lane16 * 8);
      }
#pragma unroll
      for (int i = 0; i < 5; ++i) {
        if (i >= NB) break;
        h2[i] = *(const bf16x8*)(H + (size_t)iC[i] * 384 + 256 + lane16 * 8);
      }
#pragma unroll
      for (int i = 0; i < 5; ++i) {
        if (i >= NB) break;
        int pos = (i0 + i) * 16 + pgrp;
        bool valid = (uu[i] >= 0) & (uu[i] < S_);
        float z[8];
#pragma unroll
        for (int j = 0; j < 8; ++j) {
          float y = bf2f((unsigned short)h0[i][j]) + bf2f((unsigned short)h1[i][j])
                  + bf2f((unsigned short)h2[i][j]);
          z[j] = fmaxf(aa[j] * y + cc[j], 0.f);
        }
        u32x4 pk;
        pk[0] = (unsigned)f2bf(z[0]) | ((unsigned)f2bf(z[1]) << 16);
        pk[1] = (unsigned)f2bf(z[2]) | ((unsigned)f2bf(z[3]) << 16);
        pk[2] = (unsigned)f2bf(z[4]) | ((unsigned)f2bf(z[5]) << 16);
        pk[3] = (unsigned)f2bf(z[6]) | ((unsigned)f2bf(z[7]) << 16);
        if (!valid) pk = (u32x4){0, 0, 0, 0};
        if (pos < CH_ + 2) {
          int byte = (lane16 * 16) ^ ((pos & 15) << 4);   // 4-bit XOR swizzle
          *(u32x4*)((char*)z2s + pos * 256 + byte) = pk;
        }
      }
    }
  }
  __syncthreads();

  // ---- phase 2: MFMA. A preloaded per kh-half; B from LDS only ----
  int wave = tid >> 6, lane = tid & 63;
  int rc = lane & 15, kgrp = lane >> 4;
  int q0 = wave * 32;
  f32x4 acc[2][8];
#pragma unroll
  for (int qt = 0; qt < 2; ++qt)
#pragma unroll
    for (int nt = 0; nt < 8; ++nt) acc[qt][nt] = (f32x4){0.f, 0.f, 0.f, 0.f};

  const unsigned short* A0 = W3r + (size_t)(q0 +  0 + rc) * 384 + kgrp * 8;
  const unsigned short* A1 = W3r + (size_t)(q0 + 16 + rc) * 384 + kgrp * 8;
#pragma unroll
  for (int kh = 0; kh < 2; ++kh) {
    bf16x8 af0[6], af1[6];
#pragma unroll
    for (int s6 = 0; s6 < 6; ++s6) {
      af0[s6] = *(const bf16x8*)(A0 + (kh * 6 + s6) * 32);
      af1[s6] = *(const bf16x8*)(A1 + (kh * 6 + s6) * 32);
    }
#pragma unroll
    for (int s6 = 0; s6 < 6; ++s6) {
      int st = kh * 6 + s6;
      int k = st >> 2, pb = st & 3;
      int pbyte = pb * 64 + kgrp * 16;
#pragma unroll
      for (int nt = 0; nt < 8; ++nt) {
        int pos  = nt * 16 + rc + k;
        bf16x8 bfr = *(const bf16x8*)((const char*)z2s + pos * 256 + (pbyte ^ ((pos & 15) << 4)));
        acc[0][nt] = __builtin_amdgcn_mfma_f32_16x16x32_bf16(af0[s6], bfr, acc[0][nt], 0, 0, 0);
        acc[1][nt] = __builtin_amdgcn_mfma_f32_16x16x32_bf16(af1[s6], bfr, acc[1][nt], 0, 0, 0);
      }
    }
  }

  // ---- epilogue: +b3, ReLU, sum over 128 pos (8 tiles + shfl over rc), store ----
#pragma unroll
  for (int qt = 0; qt < 2; ++qt) {
    float p[4];
    const float4 b3q = *(const float4*)(b3 + q0 + qt * 16 + kgrp * 4);
#pragma unroll
    for (int r = 0; r < 4; ++r) p[r] = 0.f;
#pragma unroll
    for (int nt = 0; nt < 8; ++nt) {
      p[0] += fmaxf(acc[qt][nt][0] + b3q.x, 0.f);
      p[1] += fmaxf(acc[qt][nt][1] + b3q.y, 0.f);
      p[2] += fmaxf(acc[qt][nt][2] + b3q.z, 0.f);
      p[3] += fmaxf(acc[qt][nt][3] + b3q.w, 0.f);
    }
#pragma unroll
    for (int off = 1; off < 16; off <<= 1) {
      p[0] += __shfl_xor(p[0], off); p[1] += __shfl_xor(p[1], off);
      p[2] += __shfl_xor(p[2], off); p[3] += __shfl_xor(p[3], off);
    }
    if (rc == 0) {
      float* dst = part + ((size_t)b * NCHUNK_ + chunk) * C2_ + q0 + qt * 16 + kgrp * 4;
      dst[0] = p[0]; dst[1] = p[1]; dst[2] = p[2]; dst[3] = p[3];
    }
  }
}

// ---------------- K6: partial reduce + social finalize + output GEMV ----------------
__global__ void k_final(const float* __restrict__ part,
      const int* __restrict__ socC, const int* __restrict__ socS,
      const int* __restrict__ socF, const int* __restrict__ socL,
      const float* __restrict__ baseline,
      const float* __restrict__ Ws, const float* __restrict__ bs,
      const float* __restrict__ Wo, const float* __restrict__ bo,
      float* __restrict__ out) {
  int b = blockIdx.x, q = threadIdx.x;             // 128 threads
  __shared__ float h[256];
  __shared__ float st3[3];
  {
    float acc = 0.f;
    const float* pb = part + (size_t)b * NCHUNK_ * C2_ + q;
#pragma unroll 8
    for (int i = 0; i < NCHUNK_; ++i) acc += pb[i * C2_];
    h[q] = acc * (1.f / S_);
  }
  if (q == 0) {
    float total = (float)socC[b], nseg = (float)socS[b];
    int first = (S_ - 1) - socF[b], last = socL[b];
    float mu   = (nseg > 0.f) ? total / fmaxf(nseg, 1.f) : 0.f;
    float gap  = (nseg > 0.f) ? (float)(last - first + 1) - total : 0.f;
    float resp = (nseg > 1.f) ? gap / fmaxf(nseg - 1.f, 1.f) : 0.f;
    st3[0] = mu; st3[1] = nseg; st3[2] = resp;
    float den = baseline[b * 3 + 0] * baseline[b * 3 + 1] + 1e-10f;
    float sws = 1.f - mu * nseg / den;
    out[B_ * C2_ + b] = fminf(fmaxf(sws, 0.f), 1.f);
  }
  __syncthreads();
  h[128 + q] = Ws[q * 3] * st3[0] + Ws[q * 3 + 1] * st3[1] + Ws[q * 3 + 2] * st3[2] + bs[q];
  __syncthreads();
  float acc = bo[q];
  const float4* Wo4 = (const float4*)(Wo + q * 256);
#pragma unroll 8
  for (int j4 = 0; j4 < 64; ++j4) {
    float4 wv = Wo4[j4];
    acc += wv.x * h[j4 * 4] + wv.y * h[j4 * 4 + 1] + wv.z * h[j4 * 4 + 2] + wv.w * h[j4 * 4 + 3];
  }
  out[b * C2_ + q] = acc;
}

// ---------------- launch ----------------
extern "C" void kernel_launch(void* const* d_in, const int* in_sizes, int n_in,
                              void* d_out, int out_size, void* d_ws, size_t ws_size,
                              hipStream_t stream) {
  const int*   ids = (const int*)  d_in[0];
  const float* bas = (const float*)d_in[1];
  const float* emb = (const float*)d_in[2];
  const float* W1  = (const float*)d_in[3];
  const float* g1  = (const float*)d_in[5];
  const float* be1 = (const float*)d_in[6];
  const float* W2  = (const float*)d_in[7];
  const float* g2  = (const float*)d_in[9];
  const float* be2 = (const float*)d_in[10];
  const float* W3  = (const float*)d_in[11];
  const float* b3  = (const float*)d_in[12];
  const float* Ws  = (const float*)d_in[13];
  const float* bs  = (const float*)d_in[14];
  const float* Wo  = (const float*)d_in[15];
  const float* bo  = (const float*)d_in[16];
  float* out = (float*)d_out;

  char* w = (char*)d_ws;
  size_t off = 0;
  auto alloc = [&](size_t bytes) -> size_t {
    size_t o = off; off = (off + bytes + 255) & ~(size_t)255; return o;
  };
  size_t o_cnt   = alloc(T_ * 4);
  size_t o_m1    = alloc(C1_ * 4);
  size_t o_v1    = alloc(C1_ * 4);
  size_t o_s2p   = alloc((size_t)NSET_ * C2_ * 4);
  size_t o_q2p   = alloc((size_t)NSET_ * C2_ * 4);
  size_t o_socC  = alloc(B_ * 4);
  size_t o_socS  = alloc(B_ * 4);
  size_t o_socF  = alloc(B_ * 4);
  size_t o_socL  = alloc(B_ * 4);
  size_t o_done1 = alloc(256);
  size_t o_done2 = alloc(256);
  size_t zeroEnd = off;                            // everything above zero-initialized
  size_t o_part  = alloc((size_t)B_ * NCHUNK_ * C2_ * 4);   // 1 MB
  size_t o_tidx  = alloc((size_t)NPOS_ * 4);
  size_t o_G     = alloc((size_t)3 * VP_ * C1_ * 4);
  size_t o_Wr2   = alloc((size_t)384 * 256 * 2);
  size_t o_W3r   = alloc((size_t)128 * 384 * 2);
  size_t o_H     = alloc((size_t)TPAD_ * 384 * 2);          // 8.2 MB
  size_t o_a1    = alloc(C1_ * 4);
  size_t o_c1    = alloc(C1_ * 4);
  size_t o_a2    = alloc(C2_ * 4);
  size_t o_c2    = alloc(C2_ * 4);
  (void)ws_size; (void)n_in; (void)in_sizes; (void)out_size;

  int*            cnt  = (int*)(w + o_cnt);
  float*          m1a  = (float*)(w + o_m1);
  float*          v1a  = (float*)(w + o_v1);
  float*          s2p  = (float*)(w + o_s2p);
  float*          q2p  = (float*)(w + o_q2p);
  int*            socC = (int*)(w + o_socC);
  int*            socS = (int*)(w + o_socS);
  int*            socF = (int*)(w + o_socF);
  int*            socL = (int*)(w + o_socL);
  int*            dn1  = (int*)(w + o_done1);
  int*            dn2  = (int*)(w + o_done2);
  float*          part = (float*)(w + o_part);
  int*            tIdx = (int*)(w + o_tidx);
  float*          G    = (float*)(w + o_G);
  unsigned short* Wr2  = (unsigned short*)(w + o_Wr2);
  unsigned short* W3r  = (unsigned short*)(w + o_W3r);
  unsigned short* H    = (unsigned short*)(w + o_H);
  float*          a1   = (float*)(w + o_a1);
  float*          c1   = (float*)(w + o_c1);
  float*          a2   = (float*)(w + o_a2);
  float*          c2p  = (float*)(w + o_c2);

  hipMemsetAsync(w, 0, zeroEnd, stream);

  k_prep  <<<834 + NPOS_ / 256, 256, 0, stream>>>(W1, emb, W2, W3, G, Wr2, W3r,
                                                  ids, tIdx, cnt, socC, socS, socF, socL);
  k_stats1<<<(T_ + 63) / 64, 256, 0, stream>>>(G, cnt, g1, be1, m1a, v1a, dn1, a1, c1);
  k_hgemm <<<dim3((TPAD_ / 16 + 3) / 4, 3), 256, 0, stream>>>(G, a1, c1, Wr2, H);
  k_stats2<<<NPOS_ / 128, 256, 0, stream>>>(tIdx, H, s2p, q2p, dn2, g2, be2, a2, c2p);
  k_conv3 <<<B_ * NCHUNK_, 256, 0, stream>>>(tIdx, H, a2, c2p, W3r, b3, part);
  k_final <<<B_, 128, 0, stream>>>(part, socC, socS, socF, socL, bas, Ws, bs, Wo, bo, out);
}